// Round 1
// baseline (3318.627 us; speedup 1.0000x reference)
//
#include <hip/hip_runtime.h>

#define N_ 32
#define C_ 64
#define F_ 128
#define T_ 256
#define O_ 128

// Block (64,4): 64 threads along t (4 t each -> full T row), 4 along o (2 o each -> 8 o per block).
// Grid (16 o-groups, 128 f, 32 n).
__global__ __launch_bounds__(256) void damp_conv_kernel(
    const float* __restrict__ x, const float* __restrict__ W,
    const float* __restrict__ b, float* __restrict__ out)
{
    __shared__ float Wl[8 * 576];  // [oo][c*9 + kh*3 + kw]

    const int ti = threadIdx.x;      // 0..63  (t direction, one wave per y)
    const int oi = threadIdx.y;      // 0..3
    const int ob = blockIdx.x;       // 0..15  o-group
    const int f  = blockIdx.y;       // 0..127
    const int n  = blockIdx.z;       // 0..31

    const int o_base = ob * 8;

    // stage W for this block's 8 output channels into LDS
    const int tl = ti + 64 * oi;
    const float* Wg = W + (size_t)o_base * 576;
    for (int i = tl; i < 8 * 576; i += 256) Wl[i] = Wg[i];
    __syncthreads();

    const int t0 = ti * 4;

    // damp(t) = (1 - 0.1*|t-128|/128) * (1 - 0.1*|t-64|/64), for t0-1 .. t0+4
    float dmp[6];
    #pragma unroll
    for (int j = 0; j < 6; ++j) {
        float tt = (float)(t0 - 1 + j);
        float term1 = 1.0f - 0.1f * fabsf(tt - 128.0f) * (1.0f / 128.0f);
        float term2 = 1.0f - 0.1f * fabsf(tt - 64.0f) * (1.0f / 64.0f);
        dmp[j] = term1 * term2;
    }

    float acc[2][4];
    #pragma unroll
    for (int oo = 0; oo < 2; ++oo)
        #pragma unroll
        for (int j = 0; j < 4; ++j) acc[oo][j] = 0.0f;

    const float* xn  = x + (size_t)n * C_ * F_ * T_;
    const float* wl0 = &Wl[(2 * oi + 0) * 576];
    const float* wl1 = &Wl[(2 * oi + 1) * 576];

    for (int c = 0; c < C_; ++c) {
        #pragma unroll
        for (int kh = 0; kh < 3; ++kh) {
            const int fr = f + kh - 1;
            if (fr < 0 || fr >= F_) continue;   // block-uniform branch (zero pad row)
            const float* xrow = xn + ((size_t)c * F_ + fr) * T_;
            float4 xc = *(const float4*)(xrow + t0);
            float xm1 = __shfl_up(xc.w, 1);    // x[t0-1] from lane ti-1
            float xp4 = __shfl_down(xc.x, 1);  // x[t0+4] from lane ti+1
            if (ti == 0)  xm1 = 0.0f;          // t = -1 pad
            if (ti == 63) xp4 = 0.0f;          // t = 256 pad
            float xv[6];
            xv[0] = xm1  * dmp[0];
            xv[1] = xc.x * dmp[1];
            xv[2] = xc.y * dmp[2];
            xv[3] = xc.z * dmp[3];
            xv[4] = xc.w * dmp[4];
            xv[5] = xp4  * dmp[5];
            const int wk = c * 9 + kh * 3;
            float w0[3], w1[3];
            #pragma unroll
            for (int kw = 0; kw < 3; ++kw) { w0[kw] = wl0[wk + kw]; w1[kw] = wl1[wk + kw]; }
            #pragma unroll
            for (int kw = 0; kw < 3; ++kw) {
                #pragma unroll
                for (int j = 0; j < 4; ++j) {
                    acc[0][j] = fmaf(xv[j + kw], w0[kw], acc[0][j]);
                    acc[1][j] = fmaf(xv[j + kw], w1[kw], acc[1][j]);
                }
            }
        }
    }

    #pragma unroll
    for (int oo = 0; oo < 2; ++oo) {
        const int o = o_base + 2 * oi + oo;
        const float bias = b[o];
        float4 r;
        r.x = acc[oo][0] + bias;
        r.y = acc[oo][1] + bias;
        r.z = acc[oo][2] + bias;
        r.w = acc[oo][3] + bias;
        float* orow = out + (((size_t)n * O_ + o) * F_ + f) * T_ + t0;
        *(float4*)orow = r;
    }
}

extern "C" void kernel_launch(void* const* d_in, const int* in_sizes, int n_in,
                              void* d_out, int out_size, void* d_ws, size_t ws_size,
                              hipStream_t stream) {
    const float* x = (const float*)d_in[0];
    const float* W = (const float*)d_in[1];
    const float* b = (const float*)d_in[2];
    float* out = (float*)d_out;
    dim3 grid(16, 128, 32);
    dim3 block(64, 4);
    hipLaunchKernelGGL(damp_conv_kernel, grid, block, 0, stream, x, W, b, out);
}

// Round 2
// 642.913 us; speedup vs baseline: 5.1619x; 5.1619x over previous
//
#include <hip/hip_runtime.h>

typedef __attribute__((ext_vector_type(8))) short bf16x8;
typedef __attribute__((ext_vector_type(4))) float f32x4;

#define CP 40   // LDS c-pitch (elems): rows 80B -> 16B-aligned, 2-way-free b128 reads
#define TL 258  // t + 2 halo

// ---- W reorder: [o][c][kh][kw] f32 -> [k9][o][c] bf16 in workspace ----
__global__ __launch_bounds__(256) void prep_w(const float* __restrict__ W,
                                              unsigned short* __restrict__ Wr) {
    int id = blockIdx.x * 256 + threadIdx.x;
    if (id >= 9 * 128 * 64) return;
    int c = id & 63, o = (id >> 6) & 127, k9 = id >> 13;
    float w = W[(o * 64 + c) * 9 + k9];
    unsigned u = __builtin_bit_cast(unsigned, w);
    unsigned short bf = (unsigned short)((u + 0x7fff + ((u >> 16) & 1)) >> 16);
    Wr[id] = bf;  // id == (k9*128 + o)*64 + c
}

// ---- main conv: block=(n,f), 8 waves, out tile 128o x 256t ----
__global__ __launch_bounds__(512) void damp_conv_mfma(
    const float* __restrict__ x, const unsigned short* __restrict__ Wr,
    const float* __restrict__ b, float* __restrict__ out)
{
    __shared__ unsigned short xs[3 * TL * CP];  // 61,920 B

    const int tid  = threadIdx.x;
    const int lane = tid & 63;
    const int wid  = tid >> 6;

    // XCD-chunked bijective swizzle: each XCD sweeps consecutive (n,f) -> f-halo L2 reuse
    const int raw     = blockIdx.x;
    const int logical = (raw & 7) * 512 + (raw >> 3);
    const int n = logical >> 7;
    const int f = logical & 127;

    const int lo16 = lane & 15;
    const int hi2  = lane >> 4;
    const int wm = wid >> 2, wn = wid & 3;
    const int m0 = wm * 64, n0 = wn * 64;

    // damp(t) for this lane's staging t positions (t_g = lane + 64*i)
    float dmp[4];
    #pragma unroll
    for (int i = 0; i < 4; ++i) {
        float tt = (float)(lane + 64 * i);
        dmp[i] = (1.0f - 0.1f * fabsf(tt - 128.f) * (1.f / 128.f))
               * (1.0f - 0.1f * fabsf(tt - 64.f) * (1.f / 64.f));
    }

    f32x4 acc[4][4];
    #pragma unroll
    for (int i = 0; i < 4; ++i)
        #pragma unroll
        for (int j = 0; j < 4; ++j)
            acc[i][j] = (f32x4){0.f, 0.f, 0.f, 0.f};

    for (int ch = 0; ch < 2; ++ch) {
        const int cc = ch * 32;
        if (ch) __syncthreads();  // protect chunk-0 readers before overwrite

        // halo zeros: t_loc 0 and 257 (global t=-1,256 always OOB)
        if (tid < 96) {
            int cpair = tid & 15, r = tid >> 4;  // r 0..5
            int f2 = r % 3, tl0 = (r >= 3) ? 257 : 0;
            *(unsigned*)&xs[(f2 * TL + tl0) * CP + 2 * cpair] = 0u;
        }

        // stage 32 channels x 3 f-rows x 256 t, transposed to [f'][t][c], damped bf16
        #pragma unroll
        for (int f2 = 0; f2 < 3; ++f2) {
            int fg = f + f2 - 1;
            bool fok = (fg >= 0) && (fg < 128);
            #pragma unroll
            for (int cp2 = 0; cp2 < 2; ++cp2) {
                int c = cc + 2 * (wid + 8 * cp2);
                const float* r0 = x + ((size_t)(n * 64 + c) * 128 + (fok ? fg : 0)) * 256;
                const float* r1 = r0 + 128 * 256;
                #pragma unroll
                for (int i = 0; i < 4; ++i) {
                    int tg = lane + 64 * i;  // lanes consecutive -> 256B coalesced
                    float va = fok ? r0[tg] * dmp[i] : 0.f;
                    float vb = fok ? r1[tg] * dmp[i] : 0.f;
                    unsigned ua = __builtin_bit_cast(unsigned, va);
                    unsigned ub = __builtin_bit_cast(unsigned, vb);
                    unsigned short ba = (unsigned short)((ua + 0x7fff + ((ua >> 16) & 1)) >> 16);
                    unsigned short bb = (unsigned short)((ub + 0x7fff + ((ub >> 16) & 1)) >> 16);
                    unsigned pk = ((unsigned)bb << 16) | (unsigned)ba;
                    *(unsigned*)&xs[(f2 * TL + tg + 1) * CP + 2 * (wid + 8 * cp2)] = pk;
                }
            }
        }
        __syncthreads();

        // 9 shifted GEMM taps over this 32-channel chunk (K=32 = 1 MFMA step)
        #pragma unroll
        for (int kh = 0; kh < 3; ++kh) {
            #pragma unroll
            for (int kw = 0; kw < 3; ++kw) {
                bf16x8 af[4], bx[4];
                #pragma unroll
                for (int fm = 0; fm < 4; ++fm) {
                    int o = m0 + fm * 16 + lo16;
                    af[fm] = *(const bf16x8*)(Wr + (((kh * 3 + kw) * 128 + o) * 64 + cc + hi2 * 8));
                }
                #pragma unroll
                for (int fn = 0; fn < 4; ++fn) {
                    int tl_ = n0 + fn * 16 + lo16 + kw;  // t_loc = t_out + kw
                    bx[fn] = *(const bf16x8*)(&xs[(kh * TL + tl_) * CP + hi2 * 8]);
                }
                #pragma unroll
                for (int fm = 0; fm < 4; ++fm)
                    #pragma unroll
                    for (int fn = 0; fn < 4; ++fn)
                        acc[fm][fn] = __builtin_amdgcn_mfma_f32_16x16x32_bf16(
                            af[fm], bx[fn], acc[fm][fn], 0, 0, 0);
            }
        }
    }

    // epilogue: D[col=lane&15 -> t][row=(lane>>4)*4+r -> o] + bias
    #pragma unroll
    for (int fm = 0; fm < 4; ++fm) {
        int obase = m0 + fm * 16 + hi2 * 4;
        #pragma unroll
        for (int r = 0; r < 4; ++r) {
            int o = obase + r;
            float bias = b[o];
            #pragma unroll
            for (int fn = 0; fn < 4; ++fn) {
                int t = n0 + fn * 16 + lo16;
                out[(((size_t)n * 128 + o) * 128 + f) * 256 + t] = acc[fm][fn][r] + bias;
            }
        }
    }
}

extern "C" void kernel_launch(void* const* d_in, const int* in_sizes, int n_in,
                              void* d_out, int out_size, void* d_ws, size_t ws_size,
                              hipStream_t stream) {
    const float* x = (const float*)d_in[0];
    const float* W = (const float*)d_in[1];
    const float* b = (const float*)d_in[2];
    float* out = (float*)d_out;
    unsigned short* Wr = (unsigned short*)d_ws;  // 147,456 B needed

    hipLaunchKernelGGL(prep_w, dim3(288), dim3(256), 0, stream, W, Wr);
    hipLaunchKernelGGL(damp_conv_mfma, dim3(4096), dim3(512), 0, stream, x, Wr, b, out);
}

// Round 3
// 482.785 us; speedup vs baseline: 6.8739x; 1.3317x over previous
//
#include <hip/hip_runtime.h>

typedef __attribute__((ext_vector_type(8))) short bf16x8;
typedef __attribute__((ext_vector_type(4))) short short4v;
typedef __attribute__((ext_vector_type(4))) float f32x4;

#define CP 36   // LDS c-pitch in shorts: 72B rows = 18 dwords, gcd(18,32)=2 -> conflict-free
#define TL 258  // t + 2 halo rows (always zero)

__device__ __forceinline__ unsigned short f2bf(float v) {
    unsigned u = __builtin_bit_cast(unsigned, v);
    return (unsigned short)((u + 0x7fffu + ((u >> 16) & 1u)) >> 16);
}

// ---- W reorder: [o][c][kh][kw] f32 -> [k9][o][c] bf16 ----
__global__ __launch_bounds__(256) void prep_w(const float* __restrict__ W,
                                              unsigned short* __restrict__ Wr) {
    int id = blockIdx.x * 256 + threadIdx.x;
    if (id >= 9 * 128 * 64) return;
    int c = id & 63, o = (id >> 6) & 127, k9 = id >> 13;
    Wr[id] = f2bf(W[(o * 64 + c) * 9 + k9]);
}

// ---- main conv: block=(n,f), 8 waves, out tile 128o x 256t ----
__global__ __launch_bounds__(512) void damp_conv_mfma(
    const float* __restrict__ x, const unsigned short* __restrict__ Wr,
    const float* __restrict__ b, float* __restrict__ out)
{
    __shared__ unsigned short xs[3 * TL * CP];  // 55,728 B

    const int tid  = threadIdx.x;
    const int lane = tid & 63;
    const int wid  = tid >> 6;
    const int q    = lane & 3;   // column within load-quad
    const int p16  = lane >> 2;  // t-quad index

    const int raw = blockIdx.x;
    const int logical = (raw & 7) * 512 + (raw >> 3);  // XCD-chunked, bijective
    const int n = logical >> 7;
    const int f = logical & 127;

    const int lo16 = lane & 15;
    const int hi2  = lane >> 4;
    const int wm = wid >> 2, wn = wid & 3;
    const int m0 = wm * 64;

    const unsigned selv = (q & 1) ? 0x07060302u : 0x05040100u;  // v_perm: pick hi/lo 16s

    // dmp[s][j]: damp(t) at t = 64s + 4*p16 + j
    float dmp[4][4];
    #pragma unroll
    for (int s = 0; s < 4; ++s)
        #pragma unroll
        for (int j = 0; j < 4; ++j) {
            float tt = (float)(64 * s + 4 * p16 + j);
            dmp[s][j] = (1.0f - 0.1f * fabsf(tt - 128.f) * (1.f / 128.f))
                      * (1.0f - 0.1f * fabsf(tt - 64.f) * (1.f / 64.f));
        }

    f32x4 acc[4][4];
    #pragma unroll
    for (int i = 0; i < 4; ++i)
        #pragma unroll
        for (int j = 0; j < 4; ++j) acc[i][j] = (f32x4){0.f, 0.f, 0.f, 0.f};

    // zero t-halo rows (t=-1 and t=256), once; chunk staging never touches them
    if (tid < 192) {
        int c = tid & 31, rsel = (tid >> 5) & 1, f2 = tid >> 6;
        xs[(f2 * TL + (rsel ? 257 : 0)) * CP + c] = 0;
    }

    // ---- staging: issue loads (12 float4) ----
    auto issue_main = [&](int cc, float4* buf) {
        #pragma unroll
        for (int g = 0; g < 3; ++g) {
            int rbase = wid * 12 + g * 4;       // uniform per wave
            int f2 = rbase >> 5, c0 = rbase & 31;
            int fg = f + f2 - 1;
            bool fok = (unsigned)fg < 128u;
            const float* src = x + (((size_t)(n * 64 + cc + c0 + q)) * 128 + (fok ? fg : 0)) * 256;
            #pragma unroll
            for (int s = 0; s < 4; ++s) {
                float4 v = fok ? *(const float4*)(src + 64 * s + 4 * p16)
                               : (float4){0.f, 0.f, 0.f, 0.f};
                buf[g * 4 + s] = v;
            }
        }
    };

    // ---- staging: damp + bf16 + quad-transpose + conflict-free LDS write ----
    auto write_main = [&](float4* buf) {
        #pragma unroll
        for (int g = 0; g < 3; ++g) {
            int rbase = wid * 12 + g * 4;
            int f2 = rbase >> 5, c0 = rbase & 31;
            #pragma unroll
            for (int s = 0; s < 4; ++s) {
                float4 v = buf[g * 4 + s];
                unsigned d0 = (unsigned)f2bf(v.x * dmp[s][0]) | ((unsigned)f2bf(v.y * dmp[s][1]) << 16);
                unsigned d1 = (unsigned)f2bf(v.z * dmp[s][2]) | ((unsigned)f2bf(v.w * dmp[s][3]) << 16);
                // 4x4 u16 quad transpose: lane ends with all 4 c at t = 64s + lane
                unsigned p0 = __shfl_xor((int)d0, 2);
                unsigned p1 = __shfl_xor((int)d1, 2);
                bool hi = (lane >> 1) & 1;
                unsigned own = hi ? d1 : d0;   // col q   @ my t-pair
                unsigned oth = hi ? p1 : p0;   // col q^2 @ my t-pair
                unsigned sown = __shfl_xor((int)own, 1);  // col q^1
                unsigned soth = __shfl_xor((int)oth, 1);  // col q^3
                bool b0 = q & 1, b1 = q & 2;
                unsigned a0 = b0 ? sown : own, a1 = b0 ? own : sown;
                unsigned g0 = b0 ? soth : oth, g1 = b0 ? oth : soth;
                unsigned e0 = b1 ? g0 : a0, e1 = b1 ? g1 : a1;
                unsigned e2 = b1 ? a0 : g0, e3 = b1 ? a1 : g1;
                unsigned r0 = __builtin_amdgcn_perm(e1, e0, selv);  // (c0,c1) @ my t
                unsigned r1 = __builtin_amdgcn_perm(e3, e2, selv);  // (c2,c3) @ my t
                unsigned* dst = (unsigned*)&xs[((f2 * TL + 1 + 64 * s + lane) * CP + c0)];
                dst[0] = r0;
                dst[1] = r1;
            }
        }
    };

    // ---- MFMA over one 32-channel chunk: 9 shifted taps ----
    auto mfma_chunk = [&](int cc) {
        #pragma unroll
        for (int kh = 0; kh < 3; ++kh) {
            #pragma unroll
            for (int kw = 0; kw < 3; ++kw) {
                bf16x8 af[4];
                #pragma unroll
                for (int fm = 0; fm < 4; ++fm) {
                    int o = m0 + fm * 16 + lo16;
                    af[fm] = *(const bf16x8*)(Wr + (((kh * 3 + kw) * 128 + o) * 64 + cc + hi2 * 8));
                }
                #pragma unroll
                for (int fn = 0; fn < 4; ++fn) {
                    int row = wn * 64 + fn * 16 + lo16 + kw;
                    const unsigned short* pb = &xs[(kh * TL + row) * CP + hi2 * 8];
                    short4v blo = *(const short4v*)pb;
                    short4v bhi = *(const short4v*)(pb + 4);
                    bf16x8 bx = {blo.x, blo.y, blo.z, blo.w, bhi.x, bhi.y, bhi.z, bhi.w};
                    #pragma unroll
                    for (int fm = 0; fm < 4; ++fm)
                        acc[fm][fn] = __builtin_amdgcn_mfma_f32_16x16x32_bf16(
                            af[fm], bx, acc[fm][fn], 0, 0, 0);
                }
            }
        }
    };

    float4 buf0[12];
    issue_main(0, buf0);
    write_main(buf0);
    __syncthreads();

    float4 buf1[12];
    issue_main(32, buf1);   // prefetch chunk 1: latency hides under chunk-0 MFMA
    mfma_chunk(0);
    __syncthreads();

    write_main(buf1);
    __syncthreads();
    mfma_chunk(32);

    // ---- epilogue ----
    #pragma unroll
    for (int fm = 0; fm < 4; ++fm) {
        int obase = m0 + fm * 16 + hi2 * 4;
        #pragma unroll
        for (int r = 0; r < 4; ++r) {
            int o = obase + r;
            float bias = b[o];
            #pragma unroll
            for (int fn = 0; fn < 4; ++fn) {
                int t = wn * 64 + fn * 16 + lo16;
                out[(((size_t)n * 128 + o) * 128 + f) * 256 + t] = acc[fm][fn][r] + bias;
            }
        }
    }
}

extern "C" void kernel_launch(void* const* d_in, const int* in_sizes, int n_in,
                              void* d_out, int out_size, void* d_ws, size_t ws_size,
                              hipStream_t stream) {
    const float* x = (const float*)d_in[0];
    const float* W = (const float*)d_in[1];
    const float* b = (const float*)d_in[2];
    float* out = (float*)d_out;
    unsigned short* Wr = (unsigned short*)d_ws;  // 147,456 B

    hipLaunchKernelGGL(prep_w, dim3(288), dim3(256), 0, stream, W, Wr);
    hipLaunchKernelGGL(damp_conv_mfma, dim3(4096), dim3(512), 0, stream, x, Wr, b, out);
}